// Round 25
// baseline (68.531 us; speedup 1.0000x reference)
//
#include <hip/hip_runtime.h>

// Problem constants (fixed shapes from setup_inputs)
#define B_    8
#define C_    512
#define N_    1024          // H*W = 32*32
#define HEADS 8
#define DH    64            // E / heads
#define E_    512
#define M_QKV 1536          // 3*E

typedef _Float16 half8  __attribute__((ext_vector_type(8)));
typedef _Float16 half4  __attribute__((ext_vector_type(4)));
typedef __bf16   bf16x8 __attribute__((ext_vector_type(8)));
typedef __bf16   bf16x4 __attribute__((ext_vector_type(4)));
typedef float    f32x4  __attribute__((ext_vector_type(4)));

typedef __attribute__((address_space(3))) char lds_t;
typedef __attribute__((address_space(1))) char glb_t;

__device__ inline short f2bfs(float f) {
    union { float f; unsigned u; } a; a.f = f;
    unsigned r = a.u + 0x7fffu + ((a.u >> 16) & 1u);   // RNE
    return (short)(r >> 16);
}
__device__ inline __bf16 f2bf(float f) {
    union { short s; __bf16 b; } o; o.s = f2bfs(f);
    return o.b;
}

// ---------------- prep: x transpose (fp16) + both weight converts, ONE launch ----------------
__global__ void prep(const float* __restrict__ x, _Float16* __restrict__ xT,
                     const float* __restrict__ w1, int n1,
                     const float* __restrict__ w2, int n2,
                     _Float16* __restrict__ o1, _Float16* __restrict__ o2) {
    int bid = blockIdx.x;
    if (bid < 4096) {
        __shared__ _Float16 tile[32][33];
        int b  = bid >> 9;
        int r  = bid & 511;
        int n0 = (r & 31) * 32, c0 = (r >> 5) * 32;
        int tx = threadIdx.x & 31, ty = threadIdx.x >> 5;    // 32 x 8
        const float* xb = x + (size_t)b * C_ * N_;
        #pragma unroll
        for (int i = 0; i < 4; i++)
            tile[ty + 8*i][tx] = (_Float16)xb[(size_t)(c0 + ty + 8*i) * N_ + n0 + tx];
        __syncthreads();
        _Float16* xTb = xT + (size_t)b * N_ * C_;
        #pragma unroll
        for (int i = 0; i < 4; i++)
            xTb[(size_t)(n0 + ty + 8*i) * C_ + c0 + tx] = tile[tx][ty + 8*i];
    } else {
        int i = (bid - 4096) * 256 + threadIdx.x;
        if (i < n1) o1[i] = (_Float16)w1[i];
        else if (i - n1 < n2) o2[i - n1] = (_Float16)w2[i - n1];
    }
}

// ============ 8-wave 128x128xK main loop, BK=32, triple-buffered, counted vmcnt ============
__device__ __forceinline__ void mm128_pipe8(
        const _Float16* __restrict__ Abase, const _Float16* __restrict__ Bbase,
        int K, _Float16* abuf, _Float16* bbuf, f32x4 (&acc)[2][4]) {
    int tid = threadIdx.x;
    int wid = tid >> 6, lane = tid & 63;
    int hi = lane >> 4, li = lane & 15;
    int wr = wid >> 1, wc = wid & 1;
    int lr = lane >> 2, lc = lane & 3;          // staging: 16 rows x 4 slots per instr
    int srcoff = 8 * (lc ^ ((lr >> 1) & 3));    // pre-swizzled source chunk (elements)
    int rswz = ((li >> 1) & 3) << 3;            // read-side XOR (elements)

    auto stage = [&](int buf, int kk) {
        int row = wid * 16;                     // wave-uniform LDS base row (8 waves x 16 rows)
        __builtin_amdgcn_global_load_lds(
            (const glb_t*)(Abase + (size_t)(row + lr) * K + kk + srcoff),
            (lds_t*)(abuf + buf * 4096 + row * 32), 16, 0, 0);
        __builtin_amdgcn_global_load_lds(
            (const glb_t*)(Bbase + (size_t)(row + lr) * K + kk + srcoff),
            (lds_t*)(bbuf + buf * 4096 + row * 32), 16, 0, 0);
    };

    int NK = K >> 5;
    stage(0, 0);
    stage(1, 32);
    int cb = 0, sb = 2;
    for (int t = 0; t < NK; t++) {
        if (t < NK - 1) asm volatile("s_waitcnt vmcnt(2)" ::: "memory");
        else            asm volatile("s_waitcnt vmcnt(0)" ::: "memory");
        __builtin_amdgcn_s_barrier();
        __builtin_amdgcn_sched_barrier(0);
        if (t + 2 < NK) stage(sb, (t + 2) * 32);

        int koff = (hi * 8) ^ rswz;
        half8 a[2], bfr[4];
        #pragma unroll
        for (int mf = 0; mf < 2; mf++)
            a[mf] = *(const half8*)(abuf + cb * 4096 + (wr*32 + mf*16 + li) * 32 + koff);
        #pragma unroll
        for (int nf = 0; nf < 4; nf++)
            bfr[nf] = *(const half8*)(bbuf + cb * 4096 + (wc*64 + nf*16 + li) * 32 + koff);
        #pragma unroll
        for (int mf = 0; mf < 2; mf++)
            #pragma unroll
            for (int nf = 0; nf < 4; nf++)
                acc[mf][nf] = __builtin_amdgcn_mfma_f32_16x16x32_f16(a[mf], bfr[nf], acc[mf][nf], 0, 0, 0);

        cb = (cb == 2) ? 0 : cb + 1;
        sb = (sb == 2) ? 0 : sb + 1;
    }
}

// ---------------- QKV GEMM (8-wave; XCD-swizzled: XCD x owns batch b=x) ----------------
__global__ __launch_bounds__(512) void qkv_gemm(
        const _Float16* __restrict__ w, const _Float16* __restrict__ xT,
        _Float16* __restrict__ qT, _Float16* __restrict__ kT, __bf16* __restrict__ v) {
    __shared__ _Float16 abuf[3 * 4096];
    __shared__ _Float16 bbuf[3 * 4096];
    int bid = blockIdx.x;
    int b  = bid & 7;
    int j  = bid >> 3;
    int mt = j >> 3;                    // 0..11
    int m0 = mt * 128;
    int n0 = (j & 7) * 128;

    f32x4 acc[2][4] = {};
    mm128_pipe8(w + (size_t)m0 * C_, xT + ((size_t)b * N_ + n0) * C_, C_, abuf, bbuf, acc);

    int wid = threadIdx.x >> 6, lane = threadIdx.x & 63;
    int hi = lane >> 4, li = lane & 15;
    int wr = wid >> 1, wc = wid & 1;
    int m_base = m0 + wr * 32, n_base = n0 + wc * 64;
    int kind = mt >> 2;                 // 0=q 1=k 2=v (block-uniform)

    if (kind < 2) {
        float sc = (kind == 0) ? 0.35355339059327373f : 1.0f;
        _Float16* dst = (kind == 0) ? qT : kT;
        #pragma unroll
        for (int nf = 0; nf < 4; nf++) {
            int n = n_base + nf * 16 + li;
            #pragma unroll
            for (int mf = 0; mf < 2; mf++) {
                int rem = (m_base + mf * 16 + hi * 4) & 511;
                int h = rem >> 6, d = rem & 63;
                uint2 u;
                asm("v_cvt_pkrtz_f16_f32 %0, %1, %2" : "=v"(u.x)
                    : "v"(acc[mf][nf][0] * sc), "v"(acc[mf][nf][1] * sc));
                asm("v_cvt_pkrtz_f16_f32 %0, %1, %2" : "=v"(u.y)
                    : "v"(acc[mf][nf][2] * sc), "v"(acc[mf][nf][3] * sc));
                *(uint2*)(dst + ((size_t)(b * HEADS + h) * N_ + n) * DH + d) = u;
            }
        }
    } else {
        #pragma unroll
        for (int nf = 0; nf < 4; nf++) {
            int n = n_base + nf * 16 + li;
            int np = (n & ~31) | (((n >> 2) & 3) << 3) | (((n >> 4) & 1) << 2) | (n & 3);
            #pragma unroll
            for (int mf = 0; mf < 2; mf++) {
                #pragma unroll
                for (int r = 0; r < 4; r++) {
                    int rem = (m_base + mf * 16 + hi * 4 + r) & 511;
                    int h = rem >> 6, d = rem & 63;
                    v[((size_t)(b * HEADS + h) * DH + d) * N_ + np] = f2bf(acc[mf][nf][r]);
                }
            }
        }
    }
}

// ---------------- Attention: 8 waves x 16 queries, KVBLK=128, XCD-swizzled (R19/R20 proven) ----------------
__global__ __launch_bounds__(512) void attn_kernel(
        const _Float16* __restrict__ qT, const _Float16* __restrict__ kT,
        const __bf16* __restrict__ v, _Float16* __restrict__ oT) {
    __shared__ _Float16 kbuf[2][64*128];    // 32 KB (paired-row K)
    __shared__ __bf16   vbuf[2][64*128];    // 32 KB

    int bid = blockIdx.x;
    int xcd = bid & 7;
    int j   = bid >> 3;
    int bh  = xcd * 8 + (j >> 3);       // b*8 + h
    int b = bh >> 3, h = bh & 7;
    int wid = threadIdx.x >> 6, lane = threadIdx.x & 63;
    int hi = lane >> 4, li = lane & 15;
    int i0 = (j & 7) * 128 + wid * 16;  // 16 queries per wave, 8 waves

    const _Float16* q_s = qT + (size_t)bh * N_ * DH;
    const _Float16* k_s = kT + (size_t)bh * N_ * DH;
    const __bf16*   v_s = v  + (size_t)bh * DH * N_;

    half8 qf0 = *(const half8*)(q_s + (size_t)(i0 + li) * DH + hi*8);
    half8 qf1 = *(const half8*)(q_s + (size_t)(i0 + li) * DH + 32 + hi*8);

    f32x4 o_acc[4] = {};
    float rsum = 0.f;

    // K read offsets (elements): row R=af*8+(li>>1), slot (li&1)*8 + (chunk^(li>>1))
    int kR    = li >> 1;
    int koff0 = kR * 128 + ((li & 1) * 8 + (hi ^ kR)) * 8;          // chunk = hi
    int koff1 = kR * 128 + ((li & 1) * 8 + ((4 + hi) ^ kR)) * 8;    // chunk = 4+hi
    // staging lane decomposition (both K and V): 4 rows x 16 slots per gload
    int lR = lane >> 4, lc16 = lane & 15;
    int rsw = li & 15;                  // V read-side slot key (full width)

    auto stage = [&](int buf, int a0) {
        #pragma unroll
        for (int jj = 0; jj < 2; jj++) {
            // K: LDS rows Rb..Rb+3 (each = 2 K rows, chunk-swizzled)
            int Rb = wid*8 + jj*4;
            int Rl = Rb + lR;
            int asrc = 2*Rl + (lc16 >> 3);
            int dsrc = ((lc16 & 7) ^ (Rl & 7)) * 8;
            __builtin_amdgcn_global_load_lds(
                (const glb_t*)(k_s + (size_t)(a0 + asrc) * DH + dsrc),
                (lds_t*)&kbuf[buf][Rb*128], 16, 0, 0);
            // V: rows rowv..rowv+3, slot c holds key-chunk c^(row&15)
            int rowv = wid*8 + jj*4;
            int rv = rowv + lR;
            int lcv = 8 * (lc16 ^ (rv & 15));
            __builtin_amdgcn_global_load_lds(
                (const glb_t*)(v_s + (size_t)rv * N_ + a0 + lcv),
                (lds_t*)&vbuf[buf][rowv*128], 16, 0, 0);
        }
    };

    stage(0, 0);
    __syncthreads();

    for (int t = 0; t < 8; t++) {
        int cb = t & 1;
        if (t < 7) stage(cb ^ 1, (t + 1) * 128);

        // ---- QK^T (S^T = K^T Q): lane -> S[a = af*16 + hi*4 + r][i = li]
        f32x4 s[8] = {};
        const _Float16* kb = &kbuf[cb][0];
        #pragma unroll
        for (int af = 0; af < 8; af++) {
            half8 kf0 = *(const half8*)(kb + af*1024 + koff0);
            half8 kf1 = *(const half8*)(kb + af*1024 + koff1);
            s[af] = __builtin_amdgcn_mfma_f32_16x16x32_f16(kf0, qf0, s[af], 0, 0, 0);
            s[af] = __builtin_amdgcn_mfma_f32_16x16x32_f16(kf1, qf1, s[af], 0, 0, 0);
        }

        // ---- P = exp(S), row-sum, pack to 4 bf16x8 A-frags (pa[q] = p[8q..8q+7])
        float pv[32];
        #pragma unroll
        for (int af = 0; af < 8; af++)
            #pragma unroll
            for (int r = 0; r < 4; r++) {
                float e = __expf(s[af][r]);
                pv[af*4 + r] = e;
                rsum += e;
            }
        bf16x8 pa[4];
        #pragma unroll
        for (int q = 0; q < 4; q++) {
            union { bf16x8 v8; unsigned u[4]; } uq;
            #pragma unroll
            for (int w = 0; w < 4; w++)
                asm("v_cvt_pk_bf16_f32 %0, %1, %2" : "=v"(uq.u[w])
                    : "v"(pv[q*8 + w*2]), "v"(pv[q*8 + w*2 + 1]));
            pa[q] = uq.v8;
        }

        // ---- PV: B-frag = one b128 read of np-slot (q*4+hi) ^ (li&15)
        #pragma unroll
        for (int df = 0; df < 4; df++) {
            const __bf16* vr = &vbuf[cb][(df*16 + li) * 128];
            #pragma unroll
            for (int q = 0; q < 4; q++) {
                bf16x8 vbq = *(const bf16x8*)(vr + ((((q*4 + hi) ^ rsw) << 3)));
                o_acc[df] = __builtin_amdgcn_mfma_f32_16x16x32_bf16(pa[q], vbq, o_acc[df], 0, 0, 0);
            }
        }
        __syncthreads();
    }

    // full row-sum per query i = li (combine 4 hi-groups), then normalize+store
    rsum += __shfl_xor(rsum, 16, 64);
    rsum += __shfl_xor(rsum, 32, 64);
    #pragma unroll
    for (int r = 0; r < 4; r++) {
        int il = hi*4 + r;
        float den = __shfl(rsum, (lane & 48) | il, 64);
        float inv = 1.0f / den;
        int n = i0 + il;
        #pragma unroll
        for (int df = 0; df < 4; df++)
            oT[((size_t)b * N_ + n) * E_ + h*DH + df*16 + li] = (_Float16)(o_acc[df][r] * inv);
    }
}

// ---------------- Output GEMM: 128x64 tiles (grid 512 = 2 blocks/CU), 8-wave ----------------
__global__ __launch_bounds__(512) void out_gemm(
        const _Float16* __restrict__ w, const _Float16* __restrict__ oT,
        const float* __restrict__ bias, const float* __restrict__ x,
        float* __restrict__ out) {
    __shared__ _Float16 abuf[3 * 4096];     // 128 x 32 per buf
    __shared__ _Float16 bbuf[3 * 2048];     // 64 x 32 per buf
    int bid = blockIdx.x;
    int b  = bid & 7;
    int j  = bid >> 3;                  // 0..63
    int c0 = (j >> 4) * 128;            // 4 c-tiles
    int n0 = (j & 15) * 64;             // 16 n-tiles

    const _Float16* Abase = w + (size_t)c0 * E_;
    const _Float16* Bbase = oT + ((size_t)b * N_ + n0) * E_;

    int tid = threadIdx.x;
    int wid = tid >> 6, lane = tid & 63;
    int hi = lane >> 4, li = lane & 15;
    int wr = wid >> 1, wc = wid & 1;
    int lr = lane >> 2, lc = lane & 3;
    int srcoff = 8 * (lc ^ ((lr >> 1) & 3));
    int rswz = ((li >> 1) & 3) << 3;

    auto stage = [&](int buf, int kk) {
        int rowa = wid * 16;
        __builtin_amdgcn_global_load_lds(
            (const glb_t*)(Abase + (size_t)(rowa + lr) * E_ + kk + srcoff),
            (lds_t*)(abuf + buf * 4096 + rowa * 32), 16, 0, 0);
        int rowb = wid * 8;
        if (lane < 32)
            __builtin_amdgcn_global_load_lds(
                (const glb_t*)(Bbase + (size_t)(rowb + lr) * E_ + kk + srcoff),
                (lds_t*)(bbuf + buf * 2048 + rowb * 32), 16, 0, 0);
    };

    f32x4 acc[2][2] = {};
    stage(0, 0);
    stage(1, 32);
    int cb = 0, sb = 2;
    for (int t = 0; t < 16; t++) {
        if (t < 15) asm volatile("s_waitcnt vmcnt(2)" ::: "memory");
        else        asm volatile("s_waitcnt vmcnt(0)" ::: "memory");
        __builtin_amdgcn_s_barrier();
        __builtin_amdgcn_sched_barrier(0);
        if (t + 2 < 16) stage(sb, (t + 2) * 32);

        int koff = (hi * 8) ^ rswz;
        half8 a[2], bfr[2];
        #pragma unroll
        for (int mf = 0; mf < 2; mf++)
            a[mf] = *(const half8*)(abuf + cb * 4096 + (wr*32 + mf*16 + li) * 32 + koff);
        #pragma unroll
        for (int nf = 0; nf < 2; nf++)
            bfr[nf] = *(const half8*)(bbuf + cb * 2048 + (wc*32 + nf*16 + li) * 32 + koff);
        #pragma unroll
        for (int mf = 0; mf < 2; mf++)
            #pragma unroll
            for (int nf = 0; nf < 2; nf++)
                acc[mf][nf] = __builtin_amdgcn_mfma_f32_16x16x32_f16(a[mf], bfr[nf], acc[mf][nf], 0, 0, 0);

        cb = (cb == 2) ? 0 : cb + 1;
        sb = (sb == 2) ? 0 : sb + 1;
    }

    int c_base = c0 + wr * 32, n_base = n0 + wc * 32;
    #pragma unroll
    for (int mf = 0; mf < 2; mf++) {
        #pragma unroll
        for (int nf = 0; nf < 2; nf++) {
            int n = n_base + nf * 16 + li;
            #pragma unroll
            for (int r = 0; r < 4; r++) {
                int c = c_base + mf * 16 + hi * 4 + r;
                size_t idx = ((size_t)b * C_ + c) * N_ + n;
                out[idx] = acc[mf][nf][r] + bias[c] + x[idx];
            }
        }
    }
}

extern "C" void kernel_launch(void* const* d_in, const int* in_sizes, int n_in,
                              void* d_out, int out_size, void* d_ws, size_t ws_size,
                              hipStream_t stream) {
    const float* x     = (const float*)d_in[0];
    const float* w_in  = (const float*)d_in[1];
    const float* w_out = (const float*)d_in[2];
    const float* b_out = (const float*)d_in[3];
    float* out = (float*)d_out;

    // Workspace layout (total ~44 MB)
    char* ws = (char*)d_ws;
    _Float16* xT      = (_Float16*)ws; ws += (size_t)B_ * N_ * C_ * 2;        // 8 MB
    _Float16* w_in_h  = (_Float16*)ws; ws += (size_t)M_QKV * C_ * 2;          // 1.5 MB
    _Float16* w_out_h = (_Float16*)ws; ws += (size_t)C_ * E_ * 2;             // 0.5 MB
    _Float16* qT      = (_Float16*)ws; ws += (size_t)B_ * HEADS * N_ * DH * 2; // 8 MB
    _Float16* kT      = (_Float16*)ws; ws += (size_t)B_ * HEADS * N_ * DH * 2; // 8 MB
    __bf16*   v       = (__bf16*)ws;   ws += (size_t)B_ * HEADS * DH * N_ * 2; // 8 MB
    _Float16* oT      = (_Float16*)ws; ws += (size_t)B_ * N_ * E_ * 2;         // 8 MB

    prep<<<8192, 256, 0, stream>>>(x, xT, w_in, M_QKV * C_, w_out, C_ * E_, w_in_h, w_out_h);

    qkv_gemm<<<768, 512, 0, stream>>>(w_in_h, xT, qT, kT, v);
    attn_kernel<<<512, 512, 0, stream>>>(qT, kT, v, oT);
    out_gemm<<<512, 512, 0, stream>>>(w_out_h, oT, b_out, x, out);
}

// Round 26
// 68.057 us; speedup vs baseline: 1.0070x; 1.0070x over previous
//
#include <hip/hip_runtime.h>

// Problem constants (fixed shapes from setup_inputs)
#define B_    8
#define C_    512
#define N_    1024          // H*W = 32*32
#define HEADS 8
#define DH    64            // E / heads
#define E_    512
#define M_QKV 1536          // 3*E

typedef _Float16 half8  __attribute__((ext_vector_type(8)));
typedef _Float16 half4  __attribute__((ext_vector_type(4)));
typedef __bf16   bf16x8 __attribute__((ext_vector_type(8)));
typedef __bf16   bf16x4 __attribute__((ext_vector_type(4)));
typedef float    f32x4  __attribute__((ext_vector_type(4)));

typedef __attribute__((address_space(3))) char lds_t;
typedef __attribute__((address_space(1))) char glb_t;

__device__ inline short f2bfs(float f) {
    union { float f; unsigned u; } a; a.f = f;
    unsigned r = a.u + 0x7fffu + ((a.u >> 16) & 1u);   // RNE
    return (short)(r >> 16);
}
__device__ inline __bf16 f2bf(float f) {
    union { short s; __bf16 b; } o; o.s = f2bfs(f);
    return o.b;
}

// ---------------- prep: x transpose (fp16) + both weight converts, ONE launch ----------------
__global__ void prep(const float* __restrict__ x, _Float16* __restrict__ xT,
                     const float* __restrict__ w1, int n1,
                     const float* __restrict__ w2, int n2,
                     _Float16* __restrict__ o1, _Float16* __restrict__ o2) {
    int bid = blockIdx.x;
    if (bid < 4096) {
        __shared__ _Float16 tile[32][33];
        int b  = bid >> 9;
        int r  = bid & 511;
        int n0 = (r & 31) * 32, c0 = (r >> 5) * 32;
        int tx = threadIdx.x & 31, ty = threadIdx.x >> 5;    // 32 x 8
        const float* xb = x + (size_t)b * C_ * N_;
        #pragma unroll
        for (int i = 0; i < 4; i++)
            tile[ty + 8*i][tx] = (_Float16)xb[(size_t)(c0 + ty + 8*i) * N_ + n0 + tx];
        __syncthreads();
        _Float16* xTb = xT + (size_t)b * N_ * C_;
        #pragma unroll
        for (int i = 0; i < 4; i++)
            xTb[(size_t)(n0 + ty + 8*i) * C_ + c0 + tx] = tile[tx][ty + 8*i];
    } else {
        int i = (bid - 4096) * 256 + threadIdx.x;
        if (i < n1) o1[i] = (_Float16)w1[i];
        else if (i - n1 < n2) o2[i - n1] = (_Float16)w2[i - n1];
    }
}

// ============ 8-wave 128x128xK main loop, BK=32, triple-buffered, counted vmcnt ============
__device__ __forceinline__ void mm128_pipe8(
        const _Float16* __restrict__ Abase, const _Float16* __restrict__ Bbase,
        int K, _Float16* abuf, _Float16* bbuf, f32x4 (&acc)[2][4]) {
    int tid = threadIdx.x;
    int wid = tid >> 6, lane = tid & 63;
    int hi = lane >> 4, li = lane & 15;
    int wr = wid >> 1, wc = wid & 1;
    int lr = lane >> 2, lc = lane & 3;          // staging: 16 rows x 4 slots per instr
    int srcoff = 8 * (lc ^ ((lr >> 1) & 3));    // pre-swizzled source chunk (elements)
    int rswz = ((li >> 1) & 3) << 3;            // read-side XOR (elements)

    auto stage = [&](int buf, int kk) {
        int row = wid * 16;                     // wave-uniform LDS base row (8 waves x 16 rows)
        __builtin_amdgcn_global_load_lds(
            (const glb_t*)(Abase + (size_t)(row + lr) * K + kk + srcoff),
            (lds_t*)(abuf + buf * 4096 + row * 32), 16, 0, 0);
        __builtin_amdgcn_global_load_lds(
            (const glb_t*)(Bbase + (size_t)(row + lr) * K + kk + srcoff),
            (lds_t*)(bbuf + buf * 4096 + row * 32), 16, 0, 0);
    };

    int NK = K >> 5;
    stage(0, 0);
    stage(1, 32);
    int cb = 0, sb = 2;
    for (int t = 0; t < NK; t++) {
        if (t < NK - 1) asm volatile("s_waitcnt vmcnt(2)" ::: "memory");
        else            asm volatile("s_waitcnt vmcnt(0)" ::: "memory");
        __builtin_amdgcn_s_barrier();
        __builtin_amdgcn_sched_barrier(0);
        if (t + 2 < NK) stage(sb, (t + 2) * 32);

        int koff = (hi * 8) ^ rswz;
        half8 a[2], bfr[4];
        #pragma unroll
        for (int mf = 0; mf < 2; mf++)
            a[mf] = *(const half8*)(abuf + cb * 4096 + (wr*32 + mf*16 + li) * 32 + koff);
        #pragma unroll
        for (int nf = 0; nf < 4; nf++)
            bfr[nf] = *(const half8*)(bbuf + cb * 4096 + (wc*64 + nf*16 + li) * 32 + koff);
        #pragma unroll
        for (int mf = 0; mf < 2; mf++)
            #pragma unroll
            for (int nf = 0; nf < 4; nf++)
                acc[mf][nf] = __builtin_amdgcn_mfma_f32_16x16x32_f16(a[mf], bfr[nf], acc[mf][nf], 0, 0, 0);

        cb = (cb == 2) ? 0 : cb + 1;
        sb = (sb == 2) ? 0 : sb + 1;
    }
}

// ---------------- QKV GEMM (8-wave; XCD-swizzled: XCD x owns batch b=x) ----------------
__global__ __launch_bounds__(512) void qkv_gemm(
        const _Float16* __restrict__ w, const _Float16* __restrict__ xT,
        _Float16* __restrict__ qT, _Float16* __restrict__ kT, __bf16* __restrict__ v) {
    __shared__ _Float16 abuf[3 * 4096];
    __shared__ _Float16 bbuf[3 * 4096];
    int bid = blockIdx.x;
    int b  = bid & 7;
    int j  = bid >> 3;
    int mt = j >> 3;                    // 0..11
    int m0 = mt * 128;
    int n0 = (j & 7) * 128;

    f32x4 acc[2][4] = {};
    mm128_pipe8(w + (size_t)m0 * C_, xT + ((size_t)b * N_ + n0) * C_, C_, abuf, bbuf, acc);

    int wid = threadIdx.x >> 6, lane = threadIdx.x & 63;
    int hi = lane >> 4, li = lane & 15;
    int wr = wid >> 1, wc = wid & 1;
    int m_base = m0 + wr * 32, n_base = n0 + wc * 64;
    int kind = mt >> 2;                 // 0=q 1=k 2=v (block-uniform)

    if (kind < 2) {
        float sc = (kind == 0) ? 0.35355339059327373f : 1.0f;
        _Float16* dst = (kind == 0) ? qT : kT;
        #pragma unroll
        for (int nf = 0; nf < 4; nf++) {
            int n = n_base + nf * 16 + li;
            #pragma unroll
            for (int mf = 0; mf < 2; mf++) {
                int rem = (m_base + mf * 16 + hi * 4) & 511;
                int h = rem >> 6, d = rem & 63;
                uint2 u;
                asm("v_cvt_pkrtz_f16_f32 %0, %1, %2" : "=v"(u.x)
                    : "v"(acc[mf][nf][0] * sc), "v"(acc[mf][nf][1] * sc));
                asm("v_cvt_pkrtz_f16_f32 %0, %1, %2" : "=v"(u.y)
                    : "v"(acc[mf][nf][2] * sc), "v"(acc[mf][nf][3] * sc));
                *(uint2*)(dst + ((size_t)(b * HEADS + h) * N_ + n) * DH + d) = u;
            }
        }
    } else {
        #pragma unroll
        for (int nf = 0; nf < 4; nf++) {
            int n = n_base + nf * 16 + li;
            int np = (n & ~31) | (((n >> 2) & 3) << 3) | (((n >> 4) & 1) << 2) | (n & 3);
            #pragma unroll
            for (int mf = 0; mf < 2; mf++) {
                #pragma unroll
                for (int r = 0; r < 4; r++) {
                    int rem = (m_base + mf * 16 + hi * 4 + r) & 511;
                    int h = rem >> 6, d = rem & 63;
                    v[((size_t)(b * HEADS + h) * DH + d) * N_ + np] = f2bf(acc[mf][nf][r]);
                }
            }
        }
    }
}

// ---------------- Attention: 8 waves x 16 queries, KVBLK=128, XCD-swizzled ----------------
// R25: + s_setprio(1) around QK and PV MFMA clusters (T5 — measured +4-7% on
// attn-shaped kernels with wave role-diversity; single-variable A/B vs R24).
__global__ __launch_bounds__(512) void attn_kernel(
        const _Float16* __restrict__ qT, const _Float16* __restrict__ kT,
        const __bf16* __restrict__ v, _Float16* __restrict__ oT) {
    __shared__ _Float16 kbuf[2][64*128];    // 32 KB (paired-row K)
    __shared__ __bf16   vbuf[2][64*128];    // 32 KB

    int bid = blockIdx.x;
    int xcd = bid & 7;
    int j   = bid >> 3;
    int bh  = xcd * 8 + (j >> 3);       // b*8 + h
    int b = bh >> 3, h = bh & 7;
    int wid = threadIdx.x >> 6, lane = threadIdx.x & 63;
    int hi = lane >> 4, li = lane & 15;
    int i0 = (j & 7) * 128 + wid * 16;  // 16 queries per wave, 8 waves

    const _Float16* q_s = qT + (size_t)bh * N_ * DH;
    const _Float16* k_s = kT + (size_t)bh * N_ * DH;
    const __bf16*   v_s = v  + (size_t)bh * DH * N_;

    half8 qf0 = *(const half8*)(q_s + (size_t)(i0 + li) * DH + hi*8);
    half8 qf1 = *(const half8*)(q_s + (size_t)(i0 + li) * DH + 32 + hi*8);

    f32x4 o_acc[4] = {};
    float rsum = 0.f;

    // K read offsets (elements): row R=af*8+(li>>1), slot (li&1)*8 + (chunk^(li>>1))
    int kR    = li >> 1;
    int koff0 = kR * 128 + ((li & 1) * 8 + (hi ^ kR)) * 8;          // chunk = hi
    int koff1 = kR * 128 + ((li & 1) * 8 + ((4 + hi) ^ kR)) * 8;    // chunk = 4+hi
    // staging lane decomposition (both K and V): 4 rows x 16 slots per gload
    int lR = lane >> 4, lc16 = lane & 15;
    int rsw = li & 15;                  // V read-side slot key (full width)

    auto stage = [&](int buf, int a0) {
        #pragma unroll
        for (int jj = 0; jj < 2; jj++) {
            // K: LDS rows Rb..Rb+3 (each = 2 K rows, chunk-swizzled)
            int Rb = wid*8 + jj*4;
            int Rl = Rb + lR;
            int asrc = 2*Rl + (lc16 >> 3);
            int dsrc = ((lc16 & 7) ^ (Rl & 7)) * 8;
            __builtin_amdgcn_global_load_lds(
                (const glb_t*)(k_s + (size_t)(a0 + asrc) * DH + dsrc),
                (lds_t*)&kbuf[buf][Rb*128], 16, 0, 0);
            // V: rows rowv..rowv+3, slot c holds key-chunk c^(row&15)
            int rowv = wid*8 + jj*4;
            int rv = rowv + lR;
            int lcv = 8 * (lc16 ^ (rv & 15));
            __builtin_amdgcn_global_load_lds(
                (const glb_t*)(v_s + (size_t)rv * N_ + a0 + lcv),
                (lds_t*)&vbuf[buf][rowv*128], 16, 0, 0);
        }
    };

    stage(0, 0);
    __syncthreads();

    for (int t = 0; t < 8; t++) {
        int cb = t & 1;
        if (t < 7) stage(cb ^ 1, (t + 1) * 128);

        // ---- QK^T (S^T = K^T Q): lane -> S[a = af*16 + hi*4 + r][i = li]
        f32x4 s[8] = {};
        const _Float16* kb = &kbuf[cb][0];
        __builtin_amdgcn_s_setprio(1);
        #pragma unroll
        for (int af = 0; af < 8; af++) {
            half8 kf0 = *(const half8*)(kb + af*1024 + koff0);
            half8 kf1 = *(const half8*)(kb + af*1024 + koff1);
            s[af] = __builtin_amdgcn_mfma_f32_16x16x32_f16(kf0, qf0, s[af], 0, 0, 0);
            s[af] = __builtin_amdgcn_mfma_f32_16x16x32_f16(kf1, qf1, s[af], 0, 0, 0);
        }
        __builtin_amdgcn_s_setprio(0);

        // ---- P = exp(S), row-sum, pack to 4 bf16x8 A-frags (pa[q] = p[8q..8q+7])
        float pv[32];
        #pragma unroll
        for (int af = 0; af < 8; af++)
            #pragma unroll
            for (int r = 0; r < 4; r++) {
                float e = __expf(s[af][r]);
                pv[af*4 + r] = e;
                rsum += e;
            }
        bf16x8 pa[4];
        #pragma unroll
        for (int q = 0; q < 4; q++) {
            union { bf16x8 v8; unsigned u[4]; } uq;
            #pragma unroll
            for (int w = 0; w < 4; w++)
                asm("v_cvt_pk_bf16_f32 %0, %1, %2" : "=v"(uq.u[w])
                    : "v"(pv[q*8 + w*2]), "v"(pv[q*8 + w*2 + 1]));
            pa[q] = uq.v8;
        }

        // ---- PV: B-frag = one b128 read of np-slot (q*4+hi) ^ (li&15)
        __builtin_amdgcn_s_setprio(1);
        #pragma unroll
        for (int df = 0; df < 4; df++) {
            const __bf16* vr = &vbuf[cb][(df*16 + li) * 128];
            #pragma unroll
            for (int q = 0; q < 4; q++) {
                bf16x8 vbq = *(const bf16x8*)(vr + ((((q*4 + hi) ^ rsw) << 3)));
                o_acc[df] = __builtin_amdgcn_mfma_f32_16x16x32_bf16(pa[q], vbq, o_acc[df], 0, 0, 0);
            }
        }
        __builtin_amdgcn_s_setprio(0);
        __syncthreads();
    }

    // full row-sum per query i = li (combine 4 hi-groups), then normalize+store
    rsum += __shfl_xor(rsum, 16, 64);
    rsum += __shfl_xor(rsum, 32, 64);
    #pragma unroll
    for (int r = 0; r < 4; r++) {
        int il = hi*4 + r;
        float den = __shfl(rsum, (lane & 48) | il, 64);
        float inv = 1.0f / den;
        int n = i0 + il;
        #pragma unroll
        for (int df = 0; df < 4; df++)
            oT[((size_t)b * N_ + n) * E_ + h*DH + df*16 + li] = (_Float16)(o_acc[df][r] * inv);
    }
}

// ---------------- Output GEMM: 128x64 tiles (grid 512 = 2 blocks/CU), 8-wave ----------------
__global__ __launch_bounds__(512) void out_gemm(
        const _Float16* __restrict__ w, const _Float16* __restrict__ oT,
        const float* __restrict__ bias, const float* __restrict__ x,
        float* __restrict__ out) {
    __shared__ _Float16 abuf[3 * 4096];     // 128 x 32 per buf
    __shared__ _Float16 bbuf[3 * 2048];     // 64 x 32 per buf
    int bid = blockIdx.x;
    int b  = bid & 7;
    int j  = bid >> 3;                  // 0..63
    int c0 = (j >> 4) * 128;            // 4 c-tiles
    int n0 = (j & 15) * 64;             // 16 n-tiles

    const _Float16* Abase = w + (size_t)c0 * E_;
    const _Float16* Bbase = oT + ((size_t)b * N_ + n0) * E_;

    int tid = threadIdx.x;
    int wid = tid >> 6, lane = tid & 63;
    int hi = lane >> 4, li = lane & 15;
    int wr = wid >> 1, wc = wid & 1;
    int lr = lane >> 2, lc = lane & 3;
    int srcoff = 8 * (lc ^ ((lr >> 1) & 3));
    int rswz = ((li >> 1) & 3) << 3;

    auto stage = [&](int buf, int kk) {
        int rowa = wid * 16;
        __builtin_amdgcn_global_load_lds(
            (const glb_t*)(Abase + (size_t)(rowa + lr) * E_ + kk + srcoff),
            (lds_t*)(abuf + buf * 4096 + rowa * 32), 16, 0, 0);
        int rowb = wid * 8;
        if (lane < 32)
            __builtin_amdgcn_global_load_lds(
                (const glb_t*)(Bbase + (size_t)(rowb + lr) * E_ + kk + srcoff),
                (lds_t*)(bbuf + buf * 2048 + rowb * 32), 16, 0, 0);
    };

    f32x4 acc[2][2] = {};
    stage(0, 0);
    stage(1, 32);
    int cb = 0, sb = 2;
    for (int t = 0; t < 16; t++) {
        if (t < 15) asm volatile("s_waitcnt vmcnt(2)" ::: "memory");
        else        asm volatile("s_waitcnt vmcnt(0)" ::: "memory");
        __builtin_amdgcn_s_barrier();
        __builtin_amdgcn_sched_barrier(0);
        if (t + 2 < 16) stage(sb, (t + 2) * 32);

        int koff = (hi * 8) ^ rswz;
        half8 a[2], bfr[2];
        #pragma unroll
        for (int mf = 0; mf < 2; mf++)
            a[mf] = *(const half8*)(abuf + cb * 4096 + (wr*32 + mf*16 + li) * 32 + koff);
        #pragma unroll
        for (int nf = 0; nf < 2; nf++)
            bfr[nf] = *(const half8*)(bbuf + cb * 2048 + (wc*32 + nf*16 + li) * 32 + koff);
        #pragma unroll
        for (int mf = 0; mf < 2; mf++)
            #pragma unroll
            for (int nf = 0; nf < 2; nf++)
                acc[mf][nf] = __builtin_amdgcn_mfma_f32_16x16x32_f16(a[mf], bfr[nf], acc[mf][nf], 0, 0, 0);

        cb = (cb == 2) ? 0 : cb + 1;
        sb = (sb == 2) ? 0 : sb + 1;
    }

    int c_base = c0 + wr * 32, n_base = n0 + wc * 32;
    #pragma unroll
    for (int mf = 0; mf < 2; mf++) {
        #pragma unroll
        for (int nf = 0; nf < 2; nf++) {
            int n = n_base + nf * 16 + li;
            #pragma unroll
            for (int r = 0; r < 4; r++) {
                int c = c_base + mf * 16 + hi * 4 + r;
                size_t idx = ((size_t)b * C_ + c) * N_ + n;
                out[idx] = acc[mf][nf][r] + bias[c] + x[idx];
            }
        }
    }
}

extern "C" void kernel_launch(void* const* d_in, const int* in_sizes, int n_in,
                              void* d_out, int out_size, void* d_ws, size_t ws_size,
                              hipStream_t stream) {
    const float* x     = (const float*)d_in[0];
    const float* w_in  = (const float*)d_in[1];
    const float* w_out = (const float*)d_in[2];
    const float* b_out = (const float*)d_in[3];
    float* out = (float*)d_out;

    // Workspace layout (total ~44 MB)
    char* ws = (char*)d_ws;
    _Float16* xT      = (_Float16*)ws; ws += (size_t)B_ * N_ * C_ * 2;        // 8 MB
    _Float16* w_in_h  = (_Float16*)ws; ws += (size_t)M_QKV * C_ * 2;          // 1.5 MB
    _Float16* w_out_h = (_Float16*)ws; ws += (size_t)C_ * E_ * 2;             // 0.5 MB
    _Float16* qT      = (_Float16*)ws; ws += (size_t)B_ * HEADS * N_ * DH * 2; // 8 MB
    _Float16* kT      = (_Float16*)ws; ws += (size_t)B_ * HEADS * N_ * DH * 2; // 8 MB
    __bf16*   v       = (__bf16*)ws;   ws += (size_t)B_ * HEADS * DH * N_ * 2; // 8 MB
    _Float16* oT      = (_Float16*)ws; ws += (size_t)B_ * N_ * E_ * 2;         // 8 MB

    prep<<<8192, 256, 0, stream>>>(x, xT, w_in, M_QKV * C_, w_out, C_ * E_, w_in_h, w_out_h);

    qkv_gemm<<<768, 512, 0, stream>>>(w_in_h, xT, qT, kT, v);
    attn_kernel<<<512, 512, 0, stream>>>(qT, kT, v, oT);
    out_gemm<<<512, 512, 0, stream>>>(w_out_h, oT, b_out, x, out);
}